// Round 18
// baseline (199.006 us; speedup 1.0000x reference)
//
#include <hip/hip_runtime.h>
#include <cstdint>
#include <cstddef>

// GAT forward on MI355X — direct-bucket scatter formulation.
// Round 18: round 14 (best known, 152.6us) + NON-TEMPORAL LOADS ONLY.
// r16 proved NT stores regress (write-through on 2-4B scatter stores);
// r17 proved un-fusing regresses (overlap > pollution). NT loads mark the
// streaming edge re-reads (102MB) and x (51MB) evict-first in L2 so they
// don't displace partially-filled bucket lines. Stores stay normal.
// Pipeline: memset(deg) -> fused(linear || scatter) -> gather.

#define PAD 48

typedef __attribute__((ext_vector_type(8))) short short8v;  // 8 bf16 (4 VGPR)
typedef __attribute__((ext_vector_type(4))) float f32x4;    // acc (4 VGPR)
typedef __attribute__((ext_vector_type(4))) int   int4v;    // NT-able int4
typedef __attribute__((ext_vector_type(4))) float float4v;  // NT-able float4

__device__ __forceinline__ unsigned short f2bf(float f) {
    unsigned u = __float_as_uint(f);
    unsigned r = u + 0x7FFFu + ((u >> 16) & 1u);   // round-to-nearest-even
    return (unsigned short)(r >> 16);
}
__device__ __forceinline__ float bf2f(unsigned short u) {
    return __uint_as_float(((unsigned)u) << 16);
}

// ---------------- Kernel 1: FUSED scatter | linear+logits (MFMA) ----------
// Supergroup of 64 blocks: rem = bid&63.
//   rem < 56: scatter unit, chunk = g*7 + (rem>>3), range = rem&7 (== bid%8).
//   rem >= 56: linear tile lin = g*8 + rem-56.
__global__ __launch_bounds__(256) void gat_linear_scatter(
    const float* __restrict__ x, const float* __restrict__ W,
    const float* __restrict__ att_src, const float* __restrict__ att_dst,
    unsigned short* __restrict__ h_bf, float* __restrict__ a_src,
    float* __restrict__ a_dst, const int* __restrict__ e_src,
    const int* __restrict__ e_dst, int* __restrict__ deg,
    int* __restrict__ esrc, int N, int E, int nChunksE, int nLin)
{
    __shared__ unsigned short Wt[64][136];
    const int bid = (int)blockIdx.x;
    const int tid = threadIdx.x;
    const int g   = bid >> 6;
    const int rem = bid & 63;

    if (rem < 56) {
        // ---- scatter role: one 1024-edge chunk, keep dst in my range.
        // NT loads: streaming edges must not evict dirty bucket lines.
        const int chunk = g * 7 + (rem >> 3);
        if (chunk >= nChunksE) return;
        const int range = rem & 7;                 // == bid % 8
        const int lo = (int)(((long long)N * range) >> 3);
        const int hi = (int)(((long long)N * (range + 1)) >> 3);

        const int b = chunk * 1024 + tid * 4;
        if (b + 3 < E) {
            int4v sv = __builtin_nontemporal_load(reinterpret_cast<const int4v*>(e_src + b));
            int4v dv = __builtin_nontemporal_load(reinterpret_cast<const int4v*>(e_dst + b));
            if (dv[0] >= lo && dv[0] < hi) esrc[dv[0] * PAD + atomicAdd(&deg[dv[0]], 1)] = sv[0];
            if (dv[1] >= lo && dv[1] < hi) esrc[dv[1] * PAD + atomicAdd(&deg[dv[1]], 1)] = sv[1];
            if (dv[2] >= lo && dv[2] < hi) esrc[dv[2] * PAD + atomicAdd(&deg[dv[2]], 1)] = sv[2];
            if (dv[3] >= lo && dv[3] < hi) esrc[dv[3] * PAD + atomicAdd(&deg[dv[3]], 1)] = sv[3];
        } else {
            for (int k = b; k < E; ++k) {
                int d = e_dst[k];
                if (d >= lo && d < hi) esrc[d * PAD + atomicAdd(&deg[d], 1)] = e_src[k];
            }
        }
        return;
    }

    // ---- linear role
    const int lin = g * 8 + rem - 56;
    if (lin >= nLin) return;
    const int lane = tid & 63;
    const int wi   = tid >> 6;

    for (int i = tid; i < 8192; i += 256) {
        const int k = i >> 6, col = i & 63;
        Wt[col][k] = f2bf(W[i]);
    }
    __syncthreads();

    const int r0   = lin * 64 + wi * 16;
    const int lrow = lane & 15;
    const int kgrp = (lane >> 4) * 8;
    const int row  = r0 + lrow;
    const int rowc = row < N ? row : N - 1;

    short8v bf[4][4];
    #pragma unroll
    for (int t = 0; t < 4; ++t)
        #pragma unroll
        for (int c = 0; c < 4; ++c)
            bf[t][c] = *reinterpret_cast<const short8v*>(&Wt[lrow + 16 * c][t * 32 + kgrp]);

    // x is a read-once stream -> NT loads (evict-first, don't displace L2)
    const float* xr = x + (size_t)rowc * 128 + kgrp;
    float4v xa[4][2];
    #pragma unroll
    for (int t = 0; t < 4; ++t) {
        xa[t][0] = __builtin_nontemporal_load(reinterpret_cast<const float4v*>(xr + t * 32));
        xa[t][1] = __builtin_nontemporal_load(reinterpret_cast<const float4v*>(xr + t * 32 + 4));
    }

    f32x4 acc[4] = {f32x4{0,0,0,0}, f32x4{0,0,0,0}, f32x4{0,0,0,0}, f32x4{0,0,0,0}};
    #pragma unroll
    for (int t = 0; t < 4; ++t) {
        short8v af;
        af[0] = (short)f2bf(xa[t][0][0]); af[1] = (short)f2bf(xa[t][0][1]);
        af[2] = (short)f2bf(xa[t][0][2]); af[3] = (short)f2bf(xa[t][0][3]);
        af[4] = (short)f2bf(xa[t][1][0]); af[5] = (short)f2bf(xa[t][1][1]);
        af[6] = (short)f2bf(xa[t][1][2]); af[7] = (short)f2bf(xa[t][1][3]);
        #pragma unroll
        for (int c = 0; c < 4; ++c)
            acc[c] = __builtin_amdgcn_mfma_f32_16x16x32_bf16(af, bf[t][c], acc[c], 0, 0, 0);
    }

    const int gg = lane >> 4;
    float attS[4], attD[4];
    #pragma unroll
    for (int c = 0; c < 4; ++c) {
        attS[c] = att_src[lrow + 16 * c];
        attD[c] = att_dst[lrow + 16 * c];
    }

    #pragma unroll
    for (int reg = 0; reg < 4; ++reg) {
        const int r = r0 + gg * 4 + reg;
        if (r < N) {   // uniform within each 16-lane group -> shfl-safe
            #pragma unroll
            for (int c = 0; c < 4; ++c) {
                const float v = acc[c][reg];
                h_bf[(size_t)r * 64 + lrow + 16 * c] = f2bf(v);   // normal store
                float vs = v * attS[c];
                float vd = v * attD[c];
                vs += __shfl_xor(vs, 1, 64); vd += __shfl_xor(vd, 1, 64);
                vs += __shfl_xor(vs, 2, 64); vd += __shfl_xor(vd, 2, 64);
                vs += __shfl_xor(vs, 4, 64); vd += __shfl_xor(vd, 4, 64);
                if ((lane & 7) == 0) {
                    const int head = ((lane & 8) >> 3) + 2 * c;
                    a_src[r * 8 + head] = vs;                     // normal store
                    a_dst[r * 8 + head] = vd;
                }
            }
        }
    }
}

// ---------------- Kernel 2: gather + softmax + ELU ----------------
// One wave per dst node; lane = head*8 + sub. Bucket at node*PAD, length
// deg[node]. Per 8-edge batch: lane reads its edge once, computes its
// (edge,head) weight; src + weight redistributed via shfl. h read as bf16.
__global__ __launch_bounds__(256) void gat_gather(
    const int* __restrict__ deg, const int* __restrict__ esrc,
    const unsigned short* __restrict__ h_bf, const float* __restrict__ a_src,
    const float* __restrict__ a_dst, const float* __restrict__ bias,
    float* __restrict__ out, int N)
{
    const int node = blockIdx.x * 4 + (threadIdx.x >> 6);
    if (node >= N) return;
    const int lane = threadIdx.x & 63;
    const int head = lane >> 3;
    const int sub  = lane & 7;
    const int gbase = lane & 56;      // first lane of my head group

    const float ad = a_dst[node * 8 + head];
    // self-loop
    float e0 = a_src[node * 8 + head] + ad;
    e0 = e0 > 0.f ? e0 : 0.2f * e0;
    float w0 = __expf(e0);
    float acc = w0 * bf2f(h_bf[(uint32_t)node * 64u + (uint32_t)lane]);
    float s = w0;

    const int cnt = deg[node];
    const int beg = node * PAD;
    for (int k = 0; k < cnt; k += 8) {
        const int ke = k + sub;
        const int kc = ke < cnt ? ke : cnt - 1;
        const int sm = esrc[beg + kc];
        float a = a_src[(uint32_t)sm * 8u + (uint32_t)head] + ad;
        a = a > 0.f ? a : 0.2f * a;
        const float wm = (ke < cnt) ? __expf(a) : 0.f;

        uint32_t hoff[8];
        #pragma unroll
        for (int u = 0; u < 8; ++u) {
            const int sb = __shfl(sm, gbase | u, 64);
            hoff[u] = (uint32_t)sb * 64u + (uint32_t)lane;
        }
        float hb[8];
        #pragma unroll
        for (int u = 0; u < 8; ++u) hb[u] = bf2f(h_bf[hoff[u]]);

        #pragma unroll
        for (int u = 0; u < 8; ++u) {
            const float w = __shfl(wm, gbase | u, 64);
            acc += w * hb[u];
            s += w;
        }
    }

    float v = acc / (s + 1e-16f) + bias[lane];
    out[(uint32_t)node * 64u + (uint32_t)lane] = v > 0.f ? v : expm1f(v);
}

extern "C" void kernel_launch(void* const* d_in, const int* in_sizes, int n_in,
                              void* d_out, int out_size, void* d_ws, size_t ws_size,
                              hipStream_t stream)
{
    const float* x       = (const float*)d_in[0];
    const float* W       = (const float*)d_in[1];
    const float* att_src = (const float*)d_in[2];
    const float* att_dst = (const float*)d_in[3];
    const float* bias    = (const float*)d_in[4];
    const int*   ei      = (const int*)d_in[5];   // int32 (JAX x64 disabled)

    const int N = in_sizes[0] / 128;
    const int E = in_sizes[5] / 2;

    float* out = (float*)d_out;

    // workspace layout (~38.8 MB at N=100k)
    unsigned short* h_bf = (unsigned short*)d_ws;          // N*64 bf16
    float* a_src    = (float*)(h_bf + (size_t)N * 64);     // N*8 f32
    float* a_dst    = a_src + (size_t)N * 8;               // N*8
    int*   deg      = (int*)(a_dst + (size_t)N * 8);       // N
    int*   esrc     = deg + N;                             // N*PAD

    const int* e_src = ei;
    const int* e_dst = ei + E;

    hipMemsetAsync(deg, 0, (size_t)N * sizeof(int), stream);

    const int nChunksE = (E + 1023) / 1024;
    const int nLin     = (N + 63) / 64;
    const int gc       = (nChunksE + 6) / 7;
    const int gl       = (nLin + 7) / 8;
    const int nSuper   = gc > gl ? gc : gl;
    gat_linear_scatter<<<nSuper * 64, 256, 0, stream>>>(
        x, W, att_src, att_dst, h_bf, a_src, a_dst,
        e_src, e_dst, deg, esrc, N, E, nChunksE, nLin);

    gat_gather<<<(N + 3) / 4, 256, 0, stream>>>(deg, esrc, h_bf, a_src, a_dst, bias, out, N);
}

// Round 19
// 152.842 us; speedup vs baseline: 1.3020x; 1.3020x over previous
//
#include <hip/hip_runtime.h>
#include <cstdint>
#include <cstddef>

// GAT forward on MI355X — direct-bucket scatter formulation.
// Round 19: REVERT to round 14 exactly (best measured: 152.6 us).
// Experiments r15-r18 (NT stores, NT loads, un-fusing) all regressed:
// - NT stores: write-through on 2-4B scatter stores -> +36 MB writes.
// - NT loads: edge re-read stream loses L2/L3 service -> scatter stalls.
// - un-fused: loses linear-under-atomic overlap (worth ~12 us).
// Operating point: fused(linear || bucket-scatter) ~80 us wall (atomic
// throughput wall ~23 G/s, linear hidden) + gather ~70 us (random-line +
// VALU mixed ceiling) + memset ~2 us.

#define PAD 48

typedef __attribute__((ext_vector_type(8))) short short8v;  // 8 bf16 (4 VGPR)
typedef __attribute__((ext_vector_type(4))) float f32x4;    // acc (4 VGPR)

__device__ __forceinline__ unsigned short f2bf(float f) {
    unsigned u = __float_as_uint(f);
    unsigned r = u + 0x7FFFu + ((u >> 16) & 1u);   // round-to-nearest-even
    return (unsigned short)(r >> 16);
}
__device__ __forceinline__ float bf2f(unsigned short u) {
    return __uint_as_float(((unsigned)u) << 16);
}

// ---------------- Kernel 1: FUSED scatter | linear+logits (MFMA) ----------
// Supergroup of 64 blocks: rem = bid&63.
//   rem < 56: scatter unit, chunk = g*7 + (rem>>3), range = rem&7 (== bid%8).
//   rem >= 56: linear tile lin = g*8 + rem-56.
__global__ __launch_bounds__(256) void gat_linear_scatter(
    const float* __restrict__ x, const float* __restrict__ W,
    const float* __restrict__ att_src, const float* __restrict__ att_dst,
    unsigned short* __restrict__ h_bf, float* __restrict__ a_src,
    float* __restrict__ a_dst, const int* __restrict__ e_src,
    const int* __restrict__ e_dst, int* __restrict__ deg,
    int* __restrict__ esrc, int N, int E, int nChunksE, int nLin)
{
    __shared__ unsigned short Wt[64][136];
    const int bid = (int)blockIdx.x;
    const int tid = threadIdx.x;
    const int g   = bid >> 6;
    const int rem = bid & 63;

    if (rem < 56) {
        // ---- scatter role: one 1024-edge chunk, keep dst in my range
        const int chunk = g * 7 + (rem >> 3);
        if (chunk >= nChunksE) return;
        const int range = rem & 7;                 // == bid % 8
        const int lo = (int)(((long long)N * range) >> 3);
        const int hi = (int)(((long long)N * (range + 1)) >> 3);

        const int b = chunk * 1024 + tid * 4;
        if (b + 3 < E) {
            int4 sv = *reinterpret_cast<const int4*>(e_src + b);
            int4 dv = *reinterpret_cast<const int4*>(e_dst + b);
            if (dv.x >= lo && dv.x < hi) esrc[dv.x * PAD + atomicAdd(&deg[dv.x], 1)] = sv.x;
            if (dv.y >= lo && dv.y < hi) esrc[dv.y * PAD + atomicAdd(&deg[dv.y], 1)] = sv.y;
            if (dv.z >= lo && dv.z < hi) esrc[dv.z * PAD + atomicAdd(&deg[dv.z], 1)] = sv.z;
            if (dv.w >= lo && dv.w < hi) esrc[dv.w * PAD + atomicAdd(&deg[dv.w], 1)] = sv.w;
        } else {
            for (int k = b; k < E; ++k) {
                int d = e_dst[k];
                if (d >= lo && d < hi) esrc[d * PAD + atomicAdd(&deg[d], 1)] = e_src[k];
            }
        }
        return;
    }

    // ---- linear role
    const int lin = g * 8 + rem - 56;
    if (lin >= nLin) return;
    const int lane = tid & 63;
    const int wi   = tid >> 6;

    for (int i = tid; i < 8192; i += 256) {
        const int k = i >> 6, col = i & 63;
        Wt[col][k] = f2bf(W[i]);
    }
    __syncthreads();

    const int r0   = lin * 64 + wi * 16;
    const int lrow = lane & 15;
    const int kgrp = (lane >> 4) * 8;
    const int row  = r0 + lrow;
    const int rowc = row < N ? row : N - 1;

    short8v bf[4][4];
    #pragma unroll
    for (int t = 0; t < 4; ++t)
        #pragma unroll
        for (int c = 0; c < 4; ++c)
            bf[t][c] = *reinterpret_cast<const short8v*>(&Wt[lrow + 16 * c][t * 32 + kgrp]);

    const float* xr = x + (size_t)rowc * 128 + kgrp;
    float4 xa[4][2];
    #pragma unroll
    for (int t = 0; t < 4; ++t) {
        xa[t][0] = *reinterpret_cast<const float4*>(xr + t * 32);
        xa[t][1] = *reinterpret_cast<const float4*>(xr + t * 32 + 4);
    }

    f32x4 acc[4] = {f32x4{0,0,0,0}, f32x4{0,0,0,0}, f32x4{0,0,0,0}, f32x4{0,0,0,0}};
    #pragma unroll
    for (int t = 0; t < 4; ++t) {
        short8v af;
        af[0] = (short)f2bf(xa[t][0].x); af[1] = (short)f2bf(xa[t][0].y);
        af[2] = (short)f2bf(xa[t][0].z); af[3] = (short)f2bf(xa[t][0].w);
        af[4] = (short)f2bf(xa[t][1].x); af[5] = (short)f2bf(xa[t][1].y);
        af[6] = (short)f2bf(xa[t][1].z); af[7] = (short)f2bf(xa[t][1].w);
        #pragma unroll
        for (int c = 0; c < 4; ++c)
            acc[c] = __builtin_amdgcn_mfma_f32_16x16x32_bf16(af, bf[t][c], acc[c], 0, 0, 0);
    }

    const int gg = lane >> 4;
    float attS[4], attD[4];
    #pragma unroll
    for (int c = 0; c < 4; ++c) {
        attS[c] = att_src[lrow + 16 * c];
        attD[c] = att_dst[lrow + 16 * c];
    }

    #pragma unroll
    for (int reg = 0; reg < 4; ++reg) {
        const int r = r0 + gg * 4 + reg;
        if (r < N) {   // uniform within each 16-lane group -> shfl-safe
            #pragma unroll
            for (int c = 0; c < 4; ++c) {
                const float v = acc[c][reg];
                h_bf[(size_t)r * 64 + lrow + 16 * c] = f2bf(v);
                float vs = v * attS[c];
                float vd = v * attD[c];
                vs += __shfl_xor(vs, 1, 64); vd += __shfl_xor(vd, 1, 64);
                vs += __shfl_xor(vs, 2, 64); vd += __shfl_xor(vd, 2, 64);
                vs += __shfl_xor(vs, 4, 64); vd += __shfl_xor(vd, 4, 64);
                if ((lane & 7) == 0) {
                    const int head = ((lane & 8) >> 3) + 2 * c;
                    a_src[r * 8 + head] = vs;
                    a_dst[r * 8 + head] = vd;
                }
            }
        }
    }
}

// ---------------- Kernel 2: gather + softmax + ELU ----------------
// One wave per dst node; lane = head*8 + sub. Bucket at node*PAD, length
// deg[node]. Per 8-edge batch: lane reads its edge once, computes its
// (edge,head) weight; src + weight redistributed via shfl. h read as bf16.
__global__ __launch_bounds__(256) void gat_gather(
    const int* __restrict__ deg, const int* __restrict__ esrc,
    const unsigned short* __restrict__ h_bf, const float* __restrict__ a_src,
    const float* __restrict__ a_dst, const float* __restrict__ bias,
    float* __restrict__ out, int N)
{
    const int node = blockIdx.x * 4 + (threadIdx.x >> 6);
    if (node >= N) return;
    const int lane = threadIdx.x & 63;
    const int head = lane >> 3;
    const int sub  = lane & 7;
    const int gbase = lane & 56;      // first lane of my head group

    const float ad = a_dst[node * 8 + head];
    // self-loop
    float e0 = a_src[node * 8 + head] + ad;
    e0 = e0 > 0.f ? e0 : 0.2f * e0;
    float w0 = __expf(e0);
    float acc = w0 * bf2f(h_bf[(uint32_t)node * 64u + (uint32_t)lane]);
    float s = w0;

    const int cnt = deg[node];
    const int beg = node * PAD;
    for (int k = 0; k < cnt; k += 8) {
        const int ke = k + sub;
        const int kc = ke < cnt ? ke : cnt - 1;
        const int sm = esrc[beg + kc];
        float a = a_src[(uint32_t)sm * 8u + (uint32_t)head] + ad;
        a = a > 0.f ? a : 0.2f * a;
        const float wm = (ke < cnt) ? __expf(a) : 0.f;

        uint32_t hoff[8];
        #pragma unroll
        for (int u = 0; u < 8; ++u) {
            const int sb = __shfl(sm, gbase | u, 64);
            hoff[u] = (uint32_t)sb * 64u + (uint32_t)lane;
        }
        float hb[8];
        #pragma unroll
        for (int u = 0; u < 8; ++u) hb[u] = bf2f(h_bf[hoff[u]]);

        #pragma unroll
        for (int u = 0; u < 8; ++u) {
            const float w = __shfl(wm, gbase | u, 64);
            acc += w * hb[u];
            s += w;
        }
    }

    float v = acc / (s + 1e-16f) + bias[lane];
    out[(uint32_t)node * 64u + (uint32_t)lane] = v > 0.f ? v : expm1f(v);
}

extern "C" void kernel_launch(void* const* d_in, const int* in_sizes, int n_in,
                              void* d_out, int out_size, void* d_ws, size_t ws_size,
                              hipStream_t stream)
{
    const float* x       = (const float*)d_in[0];
    const float* W       = (const float*)d_in[1];
    const float* att_src = (const float*)d_in[2];
    const float* att_dst = (const float*)d_in[3];
    const float* bias    = (const float*)d_in[4];
    const int*   ei      = (const int*)d_in[5];   // int32 (JAX x64 disabled)

    const int N = in_sizes[0] / 128;
    const int E = in_sizes[5] / 2;

    float* out = (float*)d_out;

    // workspace layout (~38.8 MB at N=100k)
    unsigned short* h_bf = (unsigned short*)d_ws;          // N*64 bf16
    float* a_src    = (float*)(h_bf + (size_t)N * 64);     // N*8 f32
    float* a_dst    = a_src + (size_t)N * 8;               // N*8
    int*   deg      = (int*)(a_dst + (size_t)N * 8);       // N
    int*   esrc     = deg + N;                             // N*PAD

    const int* e_src = ei;
    const int* e_dst = ei + E;

    hipMemsetAsync(deg, 0, (size_t)N * sizeof(int), stream);

    const int nChunksE = (E + 1023) / 1024;
    const int nLin     = (N + 63) / 64;
    const int gc       = (nChunksE + 6) / 7;
    const int gl       = (nLin + 7) / 8;
    const int nSuper   = gc > gl ? gc : gl;
    gat_linear_scatter<<<nSuper * 64, 256, 0, stream>>>(
        x, W, att_src, att_dst, h_bf, a_src, a_dst,
        e_src, e_dst, deg, esrc, N, E, nChunksE, nLin);

    gat_gather<<<(N + 3) / 4, 256, 0, stream>>>(deg, esrc, h_bf, a_src, a_dst, bias, out, N);
}